// Round 4
// baseline (184.063 us; speedup 1.0000x reference)
//
#include <hip/hip_runtime.h>

// Round 4: GEMMs ported to counted-vmcnt multi-phase schedule (T3+T4+T2+T5):
//   BM=256 BN=128 BK=64, 8 waves (4Mx2N), kk-split LDS halves (2 phases/K-tile),
//   per phase: swizzled ds_read_b128 x8 + stage 3 gload_lds + barrier + lgkm0 +
//   setprio{16 MFMA} + vmcnt(3) + barrier.  LDS 96KB, XOR swizzle (row&3)<<4.
// Attention (swapped-QK 32x32, in-register softmax) unchanged from round 2.
// Constants: B=8 N=1024 C=768 H=12 D=64 P=16; BH=96; padded KV MKV=1056 (1040 valid).

typedef __attribute__((ext_vector_type(8))) short short8;
typedef __attribute__((ext_vector_type(4))) float f32x4;
typedef __attribute__((ext_vector_type(16))) float f32x16;
typedef __attribute__((ext_vector_type(4))) int i32x4;

#define GLOAD_LDS16(g, l)                                              \
    __builtin_amdgcn_global_load_lds(                                  \
        (const __attribute__((address_space(1))) void*)(g),            \
        (__attribute__((address_space(3))) void*)(l), 16, 0, 0)

#define GBAR  asm volatile("s_barrier" ::: "memory")
#define LGKM0 asm volatile("s_waitcnt lgkmcnt(0)" ::: "memory")
#define VMC3  asm volatile("s_waitcnt vmcnt(3)" ::: "memory")
#define VMC0  asm volatile("s_waitcnt vmcnt(0)" ::: "memory")

__device__ __forceinline__ unsigned short f2b(float f) {
    unsigned u = __builtin_bit_cast(unsigned, f);
    u = (u + 0x7fffu + ((u >> 16) & 1u)) >> 16;
    return (unsigned short)u;
}

__device__ __forceinline__ int cvt_pk_bf16(float lo, float hi) {
    int r;
    asm("v_cvt_pk_bf16_f32 %0, %1, %2" : "=v"(r) : "v"(lo), "v"(hi));
    return r;
}

// ---------------- f32 -> bf16 convert (vectorized) ----------------
__global__ void cvt_f32_to_bf16(const float* __restrict__ in,
                                unsigned short* __restrict__ out, int n4) {
    int i = blockIdx.x * blockDim.x + threadIdx.x;
    int stride = gridDim.x * blockDim.x;
    for (; i < n4; i += stride) {
        float4 v = reinterpret_cast<const float4*>(in)[i];
        ushort4 o;
        o.x = f2b(v.x); o.y = f2b(v.y); o.z = f2b(v.z); o.w = f2b(v.w);
        reinterpret_cast<ushort4*>(out)[i] = o;
    }
}

// ------------- prefix K/V prefill + pad-row zeroing ----------------
__global__ void prefill(const float* __restrict__ pk, const float* __restrict__ pv,
                        unsigned short* __restrict__ kc, unsigned short* __restrict__ vT) {
    int idx = blockIdx.x * 256 + threadIdx.x;   // 96*32*64 total
    int d  = idx & 63;
    int j  = (idx >> 6) & 31;
    int bh = idx >> 11;
    if (bh >= 96) return;
    int h = bh % 12;
    if (j < 16) {
        kc[((size_t)bh * 1056 + j) * 64 + d]  = f2b(pk[j * 768 + h * 64 + d]);
        vT[((size_t)bh * 64 + d) * 1056 + j]  = f2b(pv[j * 768 + h * 64 + d]);
    } else {
        int row = 1040 + (j - 16);
        kc[((size_t)bh * 1056 + row) * 64 + d] = 0;
        vT[((size_t)bh * 64 + d) * 1056 + row] = 0;
    }
}

// ---------------- GEMM:  Y[m][f] = sum_k A[m][k] * W[f][k] + bias[f] ----------------
// BM=256 BN=128 BK=64; 512 threads = 8 waves (4M x 2N), wave tile 64x64.
// LDS: As[2buf][2kk][256x32], Bs[2buf][2kk][128x32]; XOR swizzle ((row&3)<<4 bytes).
// Stage lead: phase (t,kk) stages kk-half of tile t+1; consumed 2 phases later;
// vmcnt(3) per phase (3 loads/phase in flight budget). Counted, never 0 in steady.
template<int MODE, int FT>
__global__ __launch_bounds__(512, 2) void gemm8(
    const unsigned short* __restrict__ A,   // [M][K] bf16
    const unsigned short* __restrict__ W,   // [F][K] bf16
    const float* __restrict__ bias,         // [F]
    int M, int F, int K,
    unsigned short* __restrict__ qbuf,      // [96][1024][64]
    unsigned short* __restrict__ kcbuf,     // [96][1056][64]
    unsigned short* __restrict__ vtbuf,     // [96][64][1056]
    float* __restrict__ fout)               // [M][F]
{
    __shared__ __align__(16) unsigned short As[2][2][8192];  // 64KB
    __shared__ __align__(16) unsigned short Bs[2][2][4096];  // 32KB

    const int tid = threadIdx.x;
    // XCD-chunk swizzle (bijective: grid % 8 == 0)
    const int bid = (blockIdx.x & 7) * (gridDim.x >> 3) + (blockIdx.x >> 3);
    const int m0 = (bid / FT) * 256;
    const int f0 = (bid % FT) * 128;
    const int wid = tid >> 6, lane = tid & 63;
    const int wr = wid >> 1, wc = wid & 1;       // 4M x 2N
    const int lo = lane & 15, hi = lane >> 4;

    // staging: thread loads 16B chunks; row = tid/4 (+128 for 2nd A round),
    // source col pre-swizzled (involution) so linear LDS dest + swz read match.
    const int scol = ((tid & 3) ^ ((tid >> 2) & 3)) << 3;   // element offset 0..24
    // ds_read byte-in-row (swizzled): row&3 == lo&3 for all fragment rows.
    const int rdsw = ((hi ^ (lo & 3)) << 4);

#define STAGE_A(BUF, KK, KT)                                                        \
    { _Pragma("unroll") for (int r_ = 0; r_ < 2; ++r_)                              \
        GLOAD_LDS16(A + (size_t)(m0 + (tid >> 2) + r_ * 128) * K + (KT) * 64 + (KK) * 32 + scol, \
                    (char*)&As[BUF][KK][0] + tid * 16 + r_ * 8192); }
#define STAGE_B(BUF, KK, KT)                                                        \
    GLOAD_LDS16(W + (size_t)(f0 + (tid >> 2)) * K + (KT) * 64 + (KK) * 32 + scol,   \
                (char*)&Bs[BUF][KK][0] + tid * 16)

    f32x4 acc[4][4];
#pragma unroll
    for (int i = 0; i < 4; ++i)
#pragma unroll
        for (int j = 0; j < 4; ++j) acc[i][j] = (f32x4)0.f;

    const int nt = K >> 6;   // 12

    // prologue: stage tile 0 (both kk halves); wait kk0 landed, kk1 stays in flight
    STAGE_A(0, 0, 0); STAGE_B(0, 0, 0);
    STAGE_A(0, 1, 0); STAGE_B(0, 1, 0);
    VMC3; GBAR;

    for (int t = 0; t < nt; ++t) {
        const int buf = t & 1, nb = buf ^ 1;
        const bool st = (t + 1 < nt);
#pragma unroll
        for (int kk = 0; kk < 2; ++kk) {
            short8 av[4], bv[4];
#pragma unroll
            for (int i = 0; i < 4; ++i) {
                av[i] = *reinterpret_cast<const short8*>(
                    (const char*)&As[buf][kk][0] + (wr * 64 + i * 16 + lo) * 64 + rdsw);
                bv[i] = *reinterpret_cast<const short8*>(
                    (const char*)&Bs[buf][kk][0] + (wc * 64 + i * 16 + lo) * 64 + rdsw);
            }
            if (st) {
                if (kk == 0) { STAGE_A(nb, 0, t + 1); STAGE_B(nb, 0, t + 1); }
                else         { STAGE_A(nb, 1, t + 1); STAGE_B(nb, 1, t + 1); }
            }
            GBAR;
            LGKM0;
            __builtin_amdgcn_s_setprio(1);
#pragma unroll
            for (int i = 0; i < 4; ++i)
#pragma unroll
                for (int j = 0; j < 4; ++j)
                    acc[i][j] = __builtin_amdgcn_mfma_f32_16x16x32_bf16(av[i], bv[j], acc[i][j], 0, 0, 0);
            __builtin_amdgcn_s_setprio(0);
            if (t == nt - 1) {
                if (kk == 0) { VMC0; GBAR; }   // last prefetched half, nothing newer
                // (t,kk)==(nt-1,1): loop ends, no wait needed
            } else {
                VMC3; GBAR;                    // counted: keeps 1 phase of loads in flight
            }
        }
    }

    // epilogue: C row = wr*64 + mi*16 + hi*4 + r, col = wc*64 + ni*16 + lo
#pragma unroll
    for (int mi = 0; mi < 4; ++mi) {
#pragma unroll
        for (int ni = 0; ni < 4; ++ni) {
            int f = f0 + wc * 64 + ni * 16 + lo;
            float bv = bias[f];
#pragma unroll
            for (int r = 0; r < 4; ++r) {
                int m = m0 + wr * 64 + mi * 16 + hi * 4 + r;
                float val = acc[mi][ni][r] + bv;
                if (MODE == 1) {
                    fout[(size_t)m * F + f] = val;
                } else {
                    int b = m >> 10, n = m & 1023;
                    if (f < 768) {
                        int h = f >> 6, d = f & 63;
                        qbuf[((size_t)(b * 12 + h) * 1024 + n) * 64 + d] = f2b(val * 0.125f);
                    } else if (f < 1536) {
                        int f2 = f - 768; int h = f2 >> 6, d = f2 & 63;
                        kcbuf[((size_t)(b * 12 + h) * 1056 + 16 + n) * 64 + d] = f2b(val);
                    } else {
                        int f2 = f - 1536; int h = f2 >> 6, d = f2 & 63;
                        vtbuf[((size_t)(b * 12 + h) * 64 + d) * 1056 + 16 + n] = f2b(val);
                    }
                }
            }
        }
    }
#undef STAGE_A
#undef STAGE_B
}

// ---------------- flash attention: swapped-QK 32x32, 32 q-rows/wave ----------------
__global__ __launch_bounds__(256) void attn_kernel(
    const unsigned short* __restrict__ q,   // [96][1024][64] (pre-scaled by D^-0.5)
    const unsigned short* __restrict__ kc,  // [96][1056][64]
    const unsigned short* __restrict__ vT,  // [96][64][1056]
    unsigned short* __restrict__ ao)        // [8][1024][768]
{
    const int tid = threadIdx.x;
    const int w = tid >> 6, lane = tid & 63;
    const int ql = lane & 31;               // q index / K row / V^T row
    const int hi = lane >> 5;

    // XCD-chunk swizzle: 768 blocks = 8 XCDs x 96; head gets one XCD's L2.
    const int bid = (blockIdx.x & 7) * 96 + (blockIdx.x >> 3);
    const int head = bid >> 3;              // 0..95
    const int qt = (bid & 7) * 4 + w;       // 0..31 (32-row q tile)
    const int b = head / 12, h = head % 12;

    const unsigned short* qp = q + ((size_t)head * 1024 + qt * 32) * 64;
    const unsigned short* kp = kc + (size_t)head * 1056 * 64;
    const unsigned short* vp = vT + (size_t)head * 64 * 1056;

    // Q fragment (B-operand): lane holds Q[q0+ql][ks*16 + hi*8 + j]
    short8 qf[4];
#pragma unroll
    for (int ks = 0; ks < 4; ++ks)
        qf[ks] = *reinterpret_cast<const short8*>(qp + (size_t)ql * 64 + ks * 16 + hi * 8);

    f32x16 o0 = (f32x16)0.f, o1 = (f32x16)0.f;   // O^T[d][q], d-blocks 0-31 / 32-63
    float m = -1e30f, l = 0.f;

    for (int t = 0; t < 33; ++t) {
        const int kbase = t * 32;
        // ---- S^T = K·Q^T over D=64 (4 mfma) ----
        f32x16 s = (f32x16)0.f;
        __builtin_amdgcn_s_setprio(1);
#pragma unroll
        for (int ks = 0; ks < 4; ++ks) {
            short8 kf = *reinterpret_cast<const short8*>(
                kp + (size_t)(kbase + ql) * 64 + ks * 16 + hi * 8);
            s = __builtin_amdgcn_mfma_f32_32x32x16_bf16(kf, qf[ks], s, 0, 0, 0);
        }
        __builtin_amdgcn_s_setprio(0);

        if (t == 32) {   // keys 1040..1055 invalid -> regs 8..15 (in-tile key >= 16)
#pragma unroll
            for (int r = 8; r < 16; ++r) s[r] = -1e30f;
        }

        // ---- online softmax, lane-local row (q = ql) ----
        float pmax = s[0];
#pragma unroll
        for (int r = 1; r < 16; ++r) pmax = fmaxf(pmax, s[r]);
        pmax = fmaxf(pmax, __shfl_xor(pmax, 32));
        if (!__all(pmax - m <= 8.f)) {       // defer-max (T13)
            float mn = fmaxf(m, pmax);
            float cf = __expf(m - mn);
            l *= cf;
            o0 *= cf;
            o1 *= cf;
            m = mn;
        }
        float p[16];
        float ts = 0.f;
#pragma unroll
        for (int r = 0; r < 16; ++r) { p[r] = __expf(s[r] - m); ts += p[r]; }
        ts += __shfl_xor(ts, 32);
        l += ts;

        // ---- P -> bf16 B-fragments (T12: cvt_pk + cross-half shfl + hi-select) ----
        int w0 = cvt_pk_bf16(p[0],  p[1]);
        int w1 = cvt_pk_bf16(p[2],  p[3]);
        int w2 = cvt_pk_bf16(p[4],  p[5]);
        int w3 = cvt_pk_bf16(p[6],  p[7]);
        int w4 = cvt_pk_bf16(p[8],  p[9]);
        int w5 = cvt_pk_bf16(p[10], p[11]);
        int w6 = cvt_pk_bf16(p[12], p[13]);
        int w7 = cvt_pk_bf16(p[14], p[15]);
        int x0 = __shfl_xor(w0, 32), x1 = __shfl_xor(w1, 32);
        int x2 = __shfl_xor(w2, 32), x3 = __shfl_xor(w3, 32);
        int x4 = __shfl_xor(w4, 32), x5 = __shfl_xor(w5, 32);
        int x6 = __shfl_xor(w6, 32), x7 = __shfl_xor(w7, 32);
        i32x4 pw0, pw1;
        pw0[0] = hi ? x2 : w0;  pw0[1] = hi ? x3 : w1;
        pw0[2] = hi ? w2 : x0;  pw0[3] = hi ? w3 : x1;
        pw1[0] = hi ? x6 : w4;  pw1[1] = hi ? x7 : w5;
        pw1[2] = hi ? w6 : x4;  pw1[3] = hi ? w7 : x5;
        short8 pf0 = __builtin_bit_cast(short8, pw0);
        short8 pf1 = __builtin_bit_cast(short8, pw1);

        // ---- O^T += V^T · P^T (4 mfma) ----
        short8 vf00 = *reinterpret_cast<const short8*>(vp + (size_t)ql * 1056 + kbase + hi * 8);
        short8 vf01 = *reinterpret_cast<const short8*>(vp + (size_t)ql * 1056 + kbase + 16 + hi * 8);
        short8 vf10 = *reinterpret_cast<const short8*>(vp + (size_t)(32 + ql) * 1056 + kbase + hi * 8);
        short8 vf11 = *reinterpret_cast<const short8*>(vp + (size_t)(32 + ql) * 1056 + kbase + 16 + hi * 8);
        __builtin_amdgcn_s_setprio(1);
        o0 = __builtin_amdgcn_mfma_f32_32x32x16_bf16(vf00, pf0, o0, 0, 0, 0);
        o0 = __builtin_amdgcn_mfma_f32_32x32x16_bf16(vf01, pf1, o0, 0, 0, 0);
        o1 = __builtin_amdgcn_mfma_f32_32x32x16_bf16(vf10, pf0, o1, 0, 0, 0);
        o1 = __builtin_amdgcn_mfma_f32_32x32x16_bf16(vf11, pf1, o1, 0, 0, 0);
        __builtin_amdgcn_s_setprio(0);
    }

    // ---- epilogue: out[q][d], q = ql lane-local, d from regs ----
    const float rinv = 1.f / l;
    unsigned short* aop = ao + ((size_t)b * 1024 + qt * 32 + ql) * 768 + h * 64;
#pragma unroll
    for (int r = 0; r < 16; r += 2) {
        int d = (r & 3) + 8 * (r >> 2) + 4 * hi;
        unsigned lo0 = f2b(o0[r] * rinv), lo1 = f2b(o0[r + 1] * rinv);
        *reinterpret_cast<unsigned*>(aop + d) = lo0 | (lo1 << 16);
        unsigned hi0 = f2b(o1[r] * rinv), hi1 = f2b(o1[r + 1] * rinv);
        *reinterpret_cast<unsigned*>(aop + 32 + d) = hi0 | (hi1 << 16);
    }
}

extern "C" void kernel_launch(void* const* d_in, const int* in_sizes, int n_in,
                              void* d_out, int out_size, void* d_ws, size_t ws_size,
                              hipStream_t stream) {
    const float* x        = (const float*)d_in[0];
    const float* qkv_w    = (const float*)d_in[1];
    const float* qkv_b    = (const float*)d_in[2];
    const float* proj_w   = (const float*)d_in[3];
    const float* proj_b   = (const float*)d_in[4];
    const float* prefix_k = (const float*)d_in[5];
    const float* prefix_v = (const float*)d_in[6];
    float* out = (float*)d_out;

    char* ws = (char*)d_ws;
    unsigned short* xb   = (unsigned short*)(ws);               // 8192*768 bf16
    unsigned short* wqkv = (unsigned short*)(ws + 12582912);    // 2304*768
    unsigned short* wp   = (unsigned short*)(ws + 16121856);    // 768*768
    unsigned short* qb   = (unsigned short*)(ws + 17301504);    // 96*1024*64
    unsigned short* kcb  = (unsigned short*)(ws + 29884416);    // 96*1056*64
    unsigned short* vtb  = (unsigned short*)(ws + 42860544);    // 96*64*1056
    unsigned short* aob  = xb;                                  // reuse xb after QKV GEMM

    cvt_f32_to_bf16<<<1024, 256, 0, stream>>>(x, xb, 8192 * 768 / 4);
    cvt_f32_to_bf16<<<512, 256, 0, stream>>>(qkv_w, wqkv, 2304 * 768 / 4);
    cvt_f32_to_bf16<<<256, 256, 0, stream>>>(proj_w, wp, 768 * 768 / 4);
    prefill<<<768, 256, 0, stream>>>(prefix_k, prefix_v, kcb, vtb);

    // QKV: 32 m-tiles (BM=256) x 18 f-tiles (BN=128) = 576 blocks (576%8==0)
    gemm8<0, 18><<<576, 512, 0, stream>>>(xb, wqkv, qkv_b, 8192, 2304, 768,
                                          qb, kcb, vtb, nullptr);
    attn_kernel<<<768, 256, 0, stream>>>(qb, kcb, vtb, aob);
    // proj: 32 m-tiles x 6 f-tiles = 192 blocks (192%8==0)
    gemm8<1, 6><<<192, 512, 0, stream>>>(aob, wp, proj_b, 8192, 768, 768,
                                         nullptr, nullptr, nullptr, out);
}

// Round 5
// 183.028 us; speedup vs baseline: 1.0057x; 1.0057x over previous
//
#include <hip/hip_runtime.h>

// Round 5: GEMM restructured for inter-block overlap:
//   BM=BN=128, BK=64, 4 waves (2x2), ring-2 LDS 64KB -> 2 blocks/CU.
//   Tile-granular staging: 8 gload_lds for tile t+1 issued at tile-t entry,
//   vmcnt(0) only at tile end (full-tile latency cover), ONE barrier/64-K tile.
//   Both kk-halves ds_read up front; compiler inserts fine-grained lgkm waits.
// Attention (swapped-QK 32x32, in-register softmax) unchanged from round 2.
// Constants: B=8 N=1024 C=768 H=12 D=64 P=16; BH=96; padded KV MKV=1056 (1040 valid).

typedef __attribute__((ext_vector_type(8))) short short8;
typedef __attribute__((ext_vector_type(4))) float f32x4;
typedef __attribute__((ext_vector_type(16))) float f32x16;
typedef __attribute__((ext_vector_type(4))) int i32x4;

#define GLOAD_LDS16(g, l)                                              \
    __builtin_amdgcn_global_load_lds(                                  \
        (const __attribute__((address_space(1))) void*)(g),            \
        (__attribute__((address_space(3))) void*)(l), 16, 0, 0)

#define GBAR  asm volatile("s_barrier" ::: "memory")
#define VMC0  asm volatile("s_waitcnt vmcnt(0)" ::: "memory")

__device__ __forceinline__ unsigned short f2b(float f) {
    unsigned u = __builtin_bit_cast(unsigned, f);
    u = (u + 0x7fffu + ((u >> 16) & 1u)) >> 16;
    return (unsigned short)u;
}

__device__ __forceinline__ int cvt_pk_bf16(float lo, float hi) {
    int r;
    asm("v_cvt_pk_bf16_f32 %0, %1, %2" : "=v"(r) : "v"(lo), "v"(hi));
    return r;
}

// ---------------- f32 -> bf16 convert (vectorized) ----------------
__global__ void cvt_f32_to_bf16(const float* __restrict__ in,
                                unsigned short* __restrict__ out, int n4) {
    int i = blockIdx.x * blockDim.x + threadIdx.x;
    int stride = gridDim.x * blockDim.x;
    for (; i < n4; i += stride) {
        float4 v = reinterpret_cast<const float4*>(in)[i];
        ushort4 o;
        o.x = f2b(v.x); o.y = f2b(v.y); o.z = f2b(v.z); o.w = f2b(v.w);
        reinterpret_cast<ushort4*>(out)[i] = o;
    }
}

// ------------- prefix K/V prefill + pad-row zeroing ----------------
__global__ void prefill(const float* __restrict__ pk, const float* __restrict__ pv,
                        unsigned short* __restrict__ kc, unsigned short* __restrict__ vT) {
    int idx = blockIdx.x * 256 + threadIdx.x;   // 96*32*64 total
    int d  = idx & 63;
    int j  = (idx >> 6) & 31;
    int bh = idx >> 11;
    if (bh >= 96) return;
    int h = bh % 12;
    if (j < 16) {
        kc[((size_t)bh * 1056 + j) * 64 + d]  = f2b(pk[j * 768 + h * 64 + d]);
        vT[((size_t)bh * 64 + d) * 1056 + j]  = f2b(pv[j * 768 + h * 64 + d]);
    } else {
        int row = 1040 + (j - 16);
        kc[((size_t)bh * 1056 + row) * 64 + d] = 0;
        vT[((size_t)bh * 64 + d) * 1056 + row] = 0;
    }
}

// ---------------- GEMM:  Y[m][f] = sum_k A[m][k] * W[f][k] + bias[f] ----------------
// BM=BN=128, BK=64, 256 threads = 4 waves (2x2), wave tile 64x64.
// LDS: As/Bs[2 slot][2 kk][128x32] bf16 = 64KB total -> 2 blocks/CU.
// Tile t lives in slot t&1. At tile entry: issue 8 gload_lds staging t+1 into
// slot s^1 (whose tile t-1 contents were consumed before the entry barrier).
// vmcnt(0) + barrier at tile end only.
template<int MODE, int FT>
__global__ __launch_bounds__(256, 2) void gemm_dp(
    const unsigned short* __restrict__ A,   // [M][K] bf16
    const unsigned short* __restrict__ W,   // [F][K] bf16
    const float* __restrict__ bias,         // [F]
    int M, int F, int K,
    unsigned short* __restrict__ qbuf,      // [96][1024][64]
    unsigned short* __restrict__ kcbuf,     // [96][1056][64]
    unsigned short* __restrict__ vtbuf,     // [96][64][1056]
    float* __restrict__ fout)               // [M][F]
{
    __shared__ __align__(16) unsigned short As[2][2][4096];  // 32KB
    __shared__ __align__(16) unsigned short Bs[2][2][4096];  // 32KB

    const int tid = threadIdx.x;
    // XCD-chunk swizzle (bijective: grid % 8 == 0)
    const int bid = (blockIdx.x & 7) * (gridDim.x >> 3) + (blockIdx.x >> 3);
    const int m0 = (bid / FT) * 128;
    const int f0 = (bid % FT) * 128;
    const int wid = tid >> 6, lane = tid & 63;
    const int wr = wid >> 1, wc = wid & 1;
    const int lo = lane & 15, hi = lane >> 4;
    // swizzled ds_read byte offset within 64B row (matches staging involution)
    const int rdsw = ((hi ^ (lo & 3)) << 4);

    // stage tile KT into slot KT&1: per kk-half [128 rows][32 cols], 2 rounds
    // of 256x16B; source col pre-swizzled with the same involution.
#define STG(KT)                                                                  \
    { _Pragma("unroll") for (int kk_ = 0; kk_ < 2; ++kk_) {                      \
        _Pragma("unroll") for (int r_ = 0; r_ < 2; ++r_) {                       \
            int id_ = r_ * 256 + tid; int row_ = id_ >> 2;                       \
            int sc_ = (((id_ & 3) ^ (row_ & 3)) << 3);                           \
            GLOAD_LDS16(A + (size_t)(m0 + row_) * K + (KT) * 64 + kk_ * 32 + sc_,\
                        (char*)&As[(KT) & 1][kk_][0] + id_ * 16);                \
            GLOAD_LDS16(W + (size_t)(f0 + row_) * K + (KT) * 64 + kk_ * 32 + sc_,\
                        (char*)&Bs[(KT) & 1][kk_][0] + id_ * 16);                \
        } } }

    f32x4 acc[4][4];
#pragma unroll
    for (int i = 0; i < 4; ++i)
#pragma unroll
        for (int j = 0; j < 4; ++j) acc[i][j] = (f32x4)0.f;

    const int nt = K >> 6;   // 12

    STG(0);
    VMC0; GBAR;

    for (int t = 0; t < nt; ++t) {
        const int s = t & 1;
        if (t + 1 < nt) STG(t + 1);          // deep lead: waited only at tile end

        short8 av[2][4], bv[2][4];
#pragma unroll
        for (int kk = 0; kk < 2; ++kk)
#pragma unroll
            for (int i = 0; i < 4; ++i) {
                av[kk][i] = *reinterpret_cast<const short8*>(
                    (const char*)&As[s][kk][0] + (wr * 64 + i * 16 + lo) * 64 + rdsw);
                bv[kk][i] = *reinterpret_cast<const short8*>(
                    (const char*)&Bs[s][kk][0] + (wc * 64 + i * 16 + lo) * 64 + rdsw);
            }
        __builtin_amdgcn_s_setprio(1);
#pragma unroll
        for (int kk = 0; kk < 2; ++kk)
#pragma unroll
            for (int i = 0; i < 4; ++i)
#pragma unroll
                for (int j = 0; j < 4; ++j)
                    acc[i][j] = __builtin_amdgcn_mfma_f32_16x16x32_bf16(
                        av[kk][i], bv[kk][j], acc[i][j], 0, 0, 0);
        __builtin_amdgcn_s_setprio(0);

        if (t + 1 < nt) {
            VMC0;        // tile t+1's 8 loads (issued ~2 MFMA-blocks ago) landed
            GBAR;        // all waves done reading slot s & staged slot s^1
        }
    }

    // epilogue: C row = wr*64 + mi*16 + hi*4 + r, col = wc*64 + ni*16 + lo
#pragma unroll
    for (int mi = 0; mi < 4; ++mi) {
#pragma unroll
        for (int ni = 0; ni < 4; ++ni) {
            int f = f0 + wc * 64 + ni * 16 + lo;
            float bv2 = bias[f];
#pragma unroll
            for (int r = 0; r < 4; ++r) {
                int m = m0 + wr * 64 + mi * 16 + hi * 4 + r;
                float val = acc[mi][ni][r] + bv2;
                if (MODE == 1) {
                    fout[(size_t)m * F + f] = val;
                } else {
                    int b = m >> 10, n = m & 1023;
                    if (f < 768) {
                        int h = f >> 6, d = f & 63;
                        qbuf[((size_t)(b * 12 + h) * 1024 + n) * 64 + d] = f2b(val * 0.125f);
                    } else if (f < 1536) {
                        int f2 = f - 768; int h = f2 >> 6, d = f2 & 63;
                        kcbuf[((size_t)(b * 12 + h) * 1056 + 16 + n) * 64 + d] = f2b(val);
                    } else {
                        int f2 = f - 1536; int h = f2 >> 6, d = f2 & 63;
                        vtbuf[((size_t)(b * 12 + h) * 64 + d) * 1056 + 16 + n] = f2b(val);
                    }
                }
            }
        }
    }
#undef STG
}

// ---------------- flash attention: swapped-QK 32x32, 32 q-rows/wave ----------------
__global__ __launch_bounds__(256) void attn_kernel(
    const unsigned short* __restrict__ q,   // [96][1024][64] (pre-scaled by D^-0.5)
    const unsigned short* __restrict__ kc,  // [96][1056][64]
    const unsigned short* __restrict__ vT,  // [96][64][1056]
    unsigned short* __restrict__ ao)        // [8][1024][768]
{
    const int tid = threadIdx.x;
    const int w = tid >> 6, lane = tid & 63;
    const int ql = lane & 31;               // q index / K row / V^T row
    const int hi = lane >> 5;

    // XCD-chunk swizzle: 768 blocks = 8 XCDs x 96; head gets one XCD's L2.
    const int bid = (blockIdx.x & 7) * 96 + (blockIdx.x >> 3);
    const int head = bid >> 3;              // 0..95
    const int qt = (bid & 7) * 4 + w;       // 0..31 (32-row q tile)
    const int b = head / 12, h = head % 12;

    const unsigned short* qp = q + ((size_t)head * 1024 + qt * 32) * 64;
    const unsigned short* kp = kc + (size_t)head * 1056 * 64;
    const unsigned short* vp = vT + (size_t)head * 64 * 1056;

    // Q fragment (B-operand): lane holds Q[q0+ql][ks*16 + hi*8 + j]
    short8 qf[4];
#pragma unroll
    for (int ks = 0; ks < 4; ++ks)
        qf[ks] = *reinterpret_cast<const short8*>(qp + (size_t)ql * 64 + ks * 16 + hi * 8);

    f32x16 o0 = (f32x16)0.f, o1 = (f32x16)0.f;   // O^T[d][q], d-blocks 0-31 / 32-63
    float m = -1e30f, l = 0.f;

    for (int t = 0; t < 33; ++t) {
        const int kbase = t * 32;
        // ---- S^T = K·Q^T over D=64 (4 mfma) ----
        f32x16 s = (f32x16)0.f;
        __builtin_amdgcn_s_setprio(1);
#pragma unroll
        for (int ks = 0; ks < 4; ++ks) {
            short8 kf = *reinterpret_cast<const short8*>(
                kp + (size_t)(kbase + ql) * 64 + ks * 16 + hi * 8);
            s = __builtin_amdgcn_mfma_f32_32x32x16_bf16(kf, qf[ks], s, 0, 0, 0);
        }
        __builtin_amdgcn_s_setprio(0);

        if (t == 32) {   // keys 1040..1055 invalid -> regs 8..15 (in-tile key >= 16)
#pragma unroll
            for (int r = 8; r < 16; ++r) s[r] = -1e30f;
        }

        // ---- online softmax, lane-local row (q = ql) ----
        float pmax = s[0];
#pragma unroll
        for (int r = 1; r < 16; ++r) pmax = fmaxf(pmax, s[r]);
        pmax = fmaxf(pmax, __shfl_xor(pmax, 32));
        if (!__all(pmax - m <= 8.f)) {       // defer-max (T13)
            float mn = fmaxf(m, pmax);
            float cf = __expf(m - mn);
            l *= cf;
            o0 *= cf;
            o1 *= cf;
            m = mn;
        }
        float p[16];
        float ts = 0.f;
#pragma unroll
        for (int r = 0; r < 16; ++r) { p[r] = __expf(s[r] - m); ts += p[r]; }
        ts += __shfl_xor(ts, 32);
        l += ts;

        // ---- P -> bf16 B-fragments (T12: cvt_pk + cross-half shfl + hi-select) ----
        int w0 = cvt_pk_bf16(p[0],  p[1]);
        int w1 = cvt_pk_bf16(p[2],  p[3]);
        int w2 = cvt_pk_bf16(p[4],  p[5]);
        int w3 = cvt_pk_bf16(p[6],  p[7]);
        int w4 = cvt_pk_bf16(p[8],  p[9]);
        int w5 = cvt_pk_bf16(p[10], p[11]);
        int w6 = cvt_pk_bf16(p[12], p[13]);
        int w7 = cvt_pk_bf16(p[14], p[15]);
        int x0 = __shfl_xor(w0, 32), x1 = __shfl_xor(w1, 32);
        int x2 = __shfl_xor(w2, 32), x3 = __shfl_xor(w3, 32);
        int x4 = __shfl_xor(w4, 32), x5 = __shfl_xor(w5, 32);
        int x6 = __shfl_xor(w6, 32), x7 = __shfl_xor(w7, 32);
        i32x4 pw0, pw1;
        pw0[0] = hi ? x2 : w0;  pw0[1] = hi ? x3 : w1;
        pw0[2] = hi ? w2 : x0;  pw0[3] = hi ? w3 : x1;
        pw1[0] = hi ? x6 : w4;  pw1[1] = hi ? x7 : w5;
        pw1[2] = hi ? w6 : x4;  pw1[3] = hi ? w7 : x5;
        short8 pf0 = __builtin_bit_cast(short8, pw0);
        short8 pf1 = __builtin_bit_cast(short8, pw1);

        // ---- O^T += V^T · P^T (4 mfma) ----
        short8 vf00 = *reinterpret_cast<const short8*>(vp + (size_t)ql * 1056 + kbase + hi * 8);
        short8 vf01 = *reinterpret_cast<const short8*>(vp + (size_t)ql * 1056 + kbase + 16 + hi * 8);
        short8 vf10 = *reinterpret_cast<const short8*>(vp + (size_t)(32 + ql) * 1056 + kbase + hi * 8);
        short8 vf11 = *reinterpret_cast<const short8*>(vp + (size_t)(32 + ql) * 1056 + kbase + 16 + hi * 8);
        __builtin_amdgcn_s_setprio(1);
        o0 = __builtin_amdgcn_mfma_f32_32x32x16_bf16(vf00, pf0, o0, 0, 0, 0);
        o0 = __builtin_amdgcn_mfma_f32_32x32x16_bf16(vf01, pf1, o0, 0, 0, 0);
        o1 = __builtin_amdgcn_mfma_f32_32x32x16_bf16(vf10, pf0, o1, 0, 0, 0);
        o1 = __builtin_amdgcn_mfma_f32_32x32x16_bf16(vf11, pf1, o1, 0, 0, 0);
        __builtin_amdgcn_s_setprio(0);
    }

    // ---- epilogue: out[q][d], q = ql lane-local, d from regs ----
    const float rinv = 1.f / l;
    unsigned short* aop = ao + ((size_t)b * 1024 + qt * 32 + ql) * 768 + h * 64;
#pragma unroll
    for (int r = 0; r < 16; r += 2) {
        int d = (r & 3) + 8 * (r >> 2) + 4 * hi;
        unsigned lo0 = f2b(o0[r] * rinv), lo1 = f2b(o0[r + 1] * rinv);
        *reinterpret_cast<unsigned*>(aop + d) = lo0 | (lo1 << 16);
        unsigned hi0 = f2b(o1[r] * rinv), hi1 = f2b(o1[r + 1] * rinv);
        *reinterpret_cast<unsigned*>(aop + 32 + d) = hi0 | (hi1 << 16);
    }
}

extern "C" void kernel_launch(void* const* d_in, const int* in_sizes, int n_in,
                              void* d_out, int out_size, void* d_ws, size_t ws_size,
                              hipStream_t stream) {
    const float* x        = (const float*)d_in[0];
    const float* qkv_w    = (const float*)d_in[1];
    const float* qkv_b    = (const float*)d_in[2];
    const float* proj_w   = (const float*)d_in[3];
    const float* proj_b   = (const float*)d_in[4];
    const float* prefix_k = (const float*)d_in[5];
    const float* prefix_v = (const float*)d_in[6];
    float* out = (float*)d_out;

    char* ws = (char*)d_ws;
    unsigned short* xb   = (unsigned short*)(ws);               // 8192*768 bf16
    unsigned short* wqkv = (unsigned short*)(ws + 12582912);    // 2304*768
    unsigned short* wp   = (unsigned short*)(ws + 16121856);    // 768*768
    unsigned short* qb   = (unsigned short*)(ws + 17301504);    // 96*1024*64
    unsigned short* kcb  = (unsigned short*)(ws + 29884416);    // 96*1056*64
    unsigned short* vtb  = (unsigned short*)(ws + 42860544);    // 96*64*1056
    unsigned short* aob  = xb;                                  // reuse xb after QKV GEMM

    cvt_f32_to_bf16<<<1024, 256, 0, stream>>>(x, xb, 8192 * 768 / 4);
    cvt_f32_to_bf16<<<512, 256, 0, stream>>>(qkv_w, wqkv, 2304 * 768 / 4);
    cvt_f32_to_bf16<<<256, 256, 0, stream>>>(proj_w, wp, 768 * 768 / 4);
    prefill<<<768, 256, 0, stream>>>(prefix_k, prefix_v, kcb, vtb);

    // QKV: 64 m-tiles x 18 f-tiles = 1152 blocks (1152%8==0)
    gemm_dp<0, 18><<<1152, 256, 0, stream>>>(xb, wqkv, qkv_b, 8192, 2304, 768,
                                             qb, kcb, vtb, nullptr);
    attn_kernel<<<768, 256, 0, stream>>>(qb, kcb, vtb, aob);
    // proj: 64 m-tiles x 6 f-tiles = 384 blocks (384%8==0)
    gemm_dp<1, 6><<<384, 256, 0, stream>>>(aob, wp, proj_b, 8192, 768, 768,
                                           nullptr, nullptr, nullptr, out);
}